// Round 1
// baseline (226.584 us; speedup 1.0000x reference)
//
#include <hip/hip_runtime.h>
#include <stdint.h>

// Problem constants
#define BB 4
#define SS 1024
#define HIDD 1024
#define NH 16
#define DHH 64

typedef __attribute__((ext_vector_type(8))) short bf16x8;
typedef __attribute__((ext_vector_type(4))) float fx4;
typedef __attribute__((ext_vector_type(4))) int ix4;

__device__ __forceinline__ float bf2f(uint16_t u) {
    union { uint32_t u; float f; } x; x.u = ((uint32_t)u) << 16; return x.f;
}
__device__ __forceinline__ uint16_t f2bf(float f) {   // RNE
    uint32_t u = __builtin_bit_cast(uint32_t, f);
    u = u + 0x7fffu + ((u >> 16) & 1u);
    return (uint16_t)(u >> 16);
}
__device__ __forceinline__ uint32_t pk_bf16(float lo, float hi) {
    uint32_t r;
    asm volatile("v_cvt_pk_bf16_f32 %0, %1, %2" : "=v"(r) : "v"(lo), "v"(hi));
    return r;
}
__device__ __forceinline__ bf16x8 mk_frag(uint32_t u0, uint32_t u1, uint32_t u2, uint32_t u3) {
    ix4 v = { (int)u0, (int)u1, (int)u2, (int)u3 };
    return __builtin_bit_cast(bf16x8, v);
}

// ---------------------------------------------------------------- cvt f32->bf16
__global__ __launch_bounds__(256) void cvt_kernel(const float* __restrict__ in,
                                                  uint16_t* __restrict__ out, int n) {
    int i = (blockIdx.x * 256 + threadIdx.x) * 4;
    if (i < n) {
        float4 v = *(const float4*)(in + i);
        uint2 p;
        p.x = pk_bf16(v.x, v.y);
        p.y = pk_bf16(v.z, v.w);
        *(uint2*)(out + i) = p;
    }
}

// ---------------------------------------------------------------- projection GEMM
// C[m,n] = sum_k X[m,k] * W[n,k] + bias[n];  out bf16 [B][NH][S][DH] (head-major)
__global__ __launch_bounds__(256) void proj_gemm(const uint16_t* __restrict__ X,
                                                 const uint16_t* __restrict__ W,
                                                 const float* __restrict__ bias,
                                                 uint16_t* __restrict__ out) {
    __shared__ uint16_t Alds[128 * 64];  // [row m][k], XOR-swizzled ^((m&7)<<4)
    __shared__ uint16_t Blds[128 * 64];  // [row n][k]
    const int tid = threadIdx.x;
    const int lane = tid & 63;
    const int wv = tid >> 6;
    const int q16 = lane & 15;
    const int hh = lane >> 4;
    const int m0 = blockIdx.x * 128;
    const int n0 = blockIdx.y * 128;
    const int wr = wv >> 1, wc = wv & 1;

    fx4 zero4 = { 0.f, 0.f, 0.f, 0.f };
    fx4 acc[4][4];
    #pragma unroll
    for (int a = 0; a < 4; a++)
        #pragma unroll
        for (int c = 0; c < 4; c++) acc[a][c] = zero4;

    const int srow = tid >> 1, shalf = tid & 1;
    for (int k0 = 0; k0 < HIDD; k0 += 64) {
        // reg-staged: 64B per thread for A and B
        const uint16_t* gA = X + (size_t)(m0 + srow) * HIDD + k0 + shalf * 32;
        const uint16_t* gB = W + (size_t)(n0 + srow) * HIDD + k0 + shalf * 32;
        #pragma unroll
        for (int i = 0; i < 4; i++) {
            uint4 va = *(const uint4*)(gA + i * 8);
            uint4 vb = *(const uint4*)(gB + i * 8);
            uint32_t bo = (uint32_t)((shalf * 64 + i * 16) ^ ((srow & 7) << 4));
            *(uint4*)((char*)Alds + srow * 128 + bo) = va;
            *(uint4*)((char*)Blds + srow * 128 + bo) = vb;
        }
        __syncthreads();
        #pragma unroll
        for (int kk = 0; kk < 2; kk++) {
            bf16x8 af[4], bf[4];
            #pragma unroll
            for (int mi = 0; mi < 4; mi++) {
                int mr = wr * 64 + mi * 16 + q16;
                af[mi] = *(const bf16x8*)((char*)Alds + mr * 128 + ((kk * 64 + hh * 16) ^ ((mr & 7) << 4)));
            }
            #pragma unroll
            for (int ni = 0; ni < 4; ni++) {
                int nr = wc * 64 + ni * 16 + q16;
                bf[ni] = *(const bf16x8*)((char*)Blds + nr * 128 + ((kk * 64 + hh * 16) ^ ((nr & 7) << 4)));
            }
            #pragma unroll
            for (int mi = 0; mi < 4; mi++)
                #pragma unroll
                for (int ni = 0; ni < 4; ni++)
                    acc[mi][ni] = __builtin_amdgcn_mfma_f32_16x16x32_bf16(af[mi], bf[ni], acc[mi][ni], 0, 0, 0);
        }
        __syncthreads();
    }
    // epilogue: C[m, n] -> out[b][h][s][d], bf16
    #pragma unroll
    for (int ni = 0; ni < 4; ni++) {
        int n = n0 + wc * 64 + ni * 16 + q16;
        float bvv = bias[n];
        int h = n >> 6, d = n & 63;
        #pragma unroll
        for (int mi = 0; mi < 4; mi++) {
            #pragma unroll
            for (int r = 0; r < 4; r++) {
                int m = m0 + wr * 64 + mi * 16 + 4 * hh + r;
                int b = m >> 10, s = m & 1023;
                out[(size_t)b * (NH * SS * DHH) + (size_t)h * (SS * DHH) + s * DHH + d] =
                    f2bf(acc[mi][ni][r] + bvv);
            }
        }
    }
}

// ---------------------------------------------------------------- V transpose: [bh][s][d] -> [bh][d][s]
__global__ __launch_bounds__(256) void vtrans(const uint16_t* __restrict__ v,
                                              uint16_t* __restrict__ vt) {
    __shared__ uint16_t t[64][72];
    const int tid = threadIdx.x;
    const int bh = blockIdx.y;
    const int s0 = blockIdx.x * 64;
    {
        int sl = tid >> 2, doff = (tid & 3) * 16;
        const uint16_t* src = v + (size_t)(bh * SS + s0 + sl) * 64 + doff;
        uint4 a = *(const uint4*)src;
        uint4 b2 = *(const uint4*)(src + 8);
        *(uint4*)&t[sl][doff] = a;
        *(uint4*)&t[sl][doff + 8] = b2;
    }
    __syncthreads();
    {
        int d = tid >> 2, soff = (tid & 3) * 16;
        uint32_t w[8];
        #pragma unroll
        for (int i = 0; i < 8; i++) {
            uint32_t lo = t[soff + 2 * i][d];
            uint32_t hi = t[soff + 2 * i + 1][d];
            w[i] = lo | (hi << 16);
        }
        uint16_t* dst = vt + (size_t)(bh * 64 + d) * SS + s0 + soff;
        uint4 o1 = { w[0], w[1], w[2], w[3] };
        uint4 o2 = { w[4], w[5], w[6], w[7] };
        *(uint4*)dst = o1;
        *(uint4*)(dst + 8) = o2;
    }
}

// ---------------------------------------------------------------- fused attention
// grid (16 q-tiles, 64 bh). 4 waves; wave w owns q rows [w*16, w*16+16).
// Swapped QK^T: D col = q = lane&15 -> softmax state is per-lane scalar.
__global__ __launch_bounds__(256) void attn_kernel(
    const uint16_t* __restrict__ qg,   // [BH][S][64]
    const uint16_t* __restrict__ kg,   // [BH][S][64]
    const uint16_t* __restrict__ vtg,  // [BH][64][S]
    const float* __restrict__ amask,   // [B][S]
    const float* __restrict__ Wrk,     // [129][64]
    const float* __restrict__ Wrv,     // [64][129]
    float* __restrict__ out)           // [B][S][NH*64]
{
    __shared__ uint16_t Klds[64 * 64];      // [m][d] swz ^((m&7)<<4)
    __shared__ uint16_t Vlds[64 * 64];      // [d][m] swz ^((d&7)<<4)
    __shared__ uint16_t sband[64][136];     // [q_local][o] final banded scores (bf16)
    __shared__ uint16_t Wrvlds[64][136];    // [d][o]

    const int tid = threadIdx.x;
    const int lane = tid & 63;
    const int wv = tid >> 6;
    const int q16 = lane & 15;
    const int hh = lane >> 4;
    const int qt = blockIdx.x;
    const int bh = blockIdx.y;
    const int b = bh >> 4;
    const int h = bh & 15;
    const int q0 = qt * 64;
    const int ql = wv * 16 + q16;
    const int qglob = q0 + ql;

    const uint16_t* qbh = qg + (size_t)bh * (SS * 64);
    const uint16_t* kbh = kg + (size_t)bh * (SS * 64);
    const uint16_t* vbh = vtg + (size_t)bh * (64 * SS);

    // Q fragments (B-operand: col=q=lane&15, k=d contiguous)
    bf16x8 qf[2];
    #pragma unroll
    for (int ks = 0; ks < 2; ks++)
        qf[ks] = *(const bf16x8*)(qbh + (size_t)qglob * 64 + ks * 32 + hh * 8);

    // stage Wrv (used only after kv loop; barriers inside loop order it)
    for (int i = tid; i < 64 * 129; i += 256) {
        int d = i / 129, o = i - d * 129;
        Wrvlds[d][o] = f2bf(Wrv[i]);
    }

    // ---- a_k = Q @ Wrk^T  ->  sband[ql][w]  (swapped: mfma(Wrk, Q) -> D[w, q])
    #pragma unroll 1
    for (int wg = 0; wg < 9; wg++) {
        fx4 a = { 0.f, 0.f, 0.f, 0.f };
        #pragma unroll
        for (int ks = 0; ks < 2; ks++) {
            int wrow = wg * 16 + q16; if (wrow > 128) wrow = 128;
            const float* p = Wrk + wrow * 64 + ks * 32 + hh * 8;
            float4 f0 = *(const float4*)p;
            float4 f1 = *(const float4*)(p + 4);
            bf16x8 af = mk_frag(pk_bf16(f0.x, f0.y), pk_bf16(f0.z, f0.w),
                                pk_bf16(f1.x, f1.y), pk_bf16(f1.z, f1.w));
            a = __builtin_amdgcn_mfma_f32_16x16x32_bf16(af, qf[ks], a, 0, 0, 0);
        }
        if (wg < 8) {
            uint2 pp;
            pp.x = pk_bf16(a[0], a[1]);
            pp.y = pk_bf16(a[2], a[3]);
            *(uint2*)&sband[ql][wg * 16 + 4 * hh] = pp;
        } else if (hh == 0) {
            sband[ql][128] = f2bf(a[0]);
        }
    }
    // poison out-of-range columns so exp() -> 0 (each wave owns its rows; no barrier needed)
    {
        int oend = hh * 33 + 33; if (oend > 129) oend = 129;
        for (int o = hh * 33; o < oend; o++) {
            int col = qglob + o - 64;
            if (col < 0 || col >= SS) sband[ql][o] = 0xff7f;  // ~ -3.39e38 bf16
        }
    }

    float m_run = -3.0e38f, l_run = 0.f;
    fx4 acc[4];
    #pragma unroll
    for (int dg = 0; dg < 4; dg++) acc[dg] = fx4{ 0.f, 0.f, 0.f, 0.f };

    for (int jt = 0; jt < 16; jt++) {
        // ---- stage K [m][d] and V^T [d][m] (reg-staged, swizzled writes)
        {
            int row = tid >> 2, part = tid & 3;
            uint32_t bo0 = (uint32_t)((part * 32) ^ ((row & 7) << 4));
            uint32_t bo1 = (uint32_t)((part * 32 + 16) ^ ((row & 7) << 4));
            const uint16_t* gk = kbh + (size_t)(jt * 64 + row) * 64 + part * 16;
            uint4 k0v = *(const uint4*)gk;
            uint4 k1v = *(const uint4*)(gk + 8);
            const uint16_t* gv = vbh + (size_t)row * SS + jt * 64 + part * 16;
            uint4 v0v = *(const uint4*)gv;
            uint4 v1v = *(const uint4*)(gv + 8);
            *(uint4*)((char*)Klds + row * 128 + bo0) = k0v;
            *(uint4*)((char*)Klds + row * 128 + bo1) = k1v;
            *(uint4*)((char*)Vlds + row * 128 + bo0) = v0v;
            *(uint4*)((char*)Vlds + row * 128 + bo1) = v1v;
        }
        __syncthreads();

        // ---- QK^T (swapped): sc[mg] cols = q, rows = m-local (4*hh+r)
        fx4 sc[4];
        #pragma unroll
        for (int mg = 0; mg < 4; mg++) {
            int mr = mg * 16 + q16;
            bf16x8 kf0 = *(const bf16x8*)((char*)Klds + mr * 128 + ((hh * 16) ^ ((mr & 7) << 4)));
            bf16x8 kf1 = *(const bf16x8*)((char*)Klds + mr * 128 + ((64 + hh * 16) ^ ((mr & 7) << 4)));
            fx4 s = { 0.f, 0.f, 0.f, 0.f };
            s = __builtin_amdgcn_mfma_f32_16x16x32_bf16(kf0, qf[0], s, 0, 0, 0);
            s = __builtin_amdgcn_mfma_f32_16x16x32_bf16(kf1, qf[1], s, 0, 0, 0);
            sc[mg] = s;
        }

        // ---- bias (banded), mask, band write-back, tile max
        const int dj = jt - qt;
        const bool band = (dj >= -1) && (dj <= 1);
        float tmax = -3.0e38f;
        #pragma unroll
        for (int mg = 0; mg < 4; mg++) {
            #pragma unroll
            for (int r = 0; r < 4; r++) {
                int m = jt * 64 + mg * 16 + 4 * hh + r;
                float s = sc[mg][r];
                int o = m - qglob + 64;
                bool inb = band && (o >= 0) && (o <= 128);
                if (inb) s += bf2f(sband[ql][o]);
                s += (1.0f - amask[b * SS + m]) * -3.0e38f;
                if (inb) sband[ql][o] = f2bf(s);
                sc[mg][r] = s;
                tmax = fmaxf(tmax, s);
            }
        }
        tmax = fmaxf(tmax, __shfl_xor(tmax, 16));
        tmax = fmaxf(tmax, __shfl_xor(tmax, 32));

        float m_new = fmaxf(m_run, tmax);
        float alpha = __expf(m_run - m_new);
        float psum = 0.f;
        uint32_t pk[4][2];
        #pragma unroll
        for (int mg = 0; mg < 4; mg++) {
            float p0 = __expf(sc[mg][0] - m_new);
            float p1 = __expf(sc[mg][1] - m_new);
            float p2 = __expf(sc[mg][2] - m_new);
            float p3 = __expf(sc[mg][3] - m_new);
            psum += (p0 + p1) + (p2 + p3);
            pk[mg][0] = pk_bf16(p0, p1);
            pk[mg][1] = pk_bf16(p2, p3);
        }
        psum += __shfl_xor(psum, 16);
        psum += __shfl_xor(psum, 32);
        l_run = l_run * alpha + psum;
        m_run = m_new;
        #pragma unroll
        for (int dg = 0; dg < 4; dg++) acc[dg] = acc[dg] * alpha;

        // ---- assemble P^T B-frags in-register (shuffles) and PV: acc^T += V^T P^T
        const int srcA = q16 + 16 * ((2 * hh) & 3);
        const int srcB = q16 + 16 * ((2 * hh + 1) & 3);
        const bool lo = (hh < 2);
        #pragma unroll
        for (int ks = 0; ks < 2; ks++) {
            uint32_t a0 = (uint32_t)__shfl((int)pk[2 * ks][0], srcA);
            uint32_t b0 = (uint32_t)__shfl((int)pk[2 * ks + 1][0], srcA);
            uint32_t a1 = (uint32_t)__shfl((int)pk[2 * ks][1], srcA);
            uint32_t b1 = (uint32_t)__shfl((int)pk[2 * ks + 1][1], srcA);
            uint32_t a2 = (uint32_t)__shfl((int)pk[2 * ks][0], srcB);
            uint32_t b2 = (uint32_t)__shfl((int)pk[2 * ks + 1][0], srcB);
            uint32_t a3 = (uint32_t)__shfl((int)pk[2 * ks][1], srcB);
            uint32_t b3 = (uint32_t)__shfl((int)pk[2 * ks + 1][1], srcB);
            bf16x8 pf = mk_frag(lo ? a0 : b0, lo ? a1 : b1, lo ? a2 : b2, lo ? a3 : b3);
            #pragma unroll
            for (int dg = 0; dg < 4; dg++) {
                int dr = dg * 16 + q16;
                bf16x8 vf = *(const bf16x8*)((char*)Vlds + dr * 128 + ((ks * 64 + hh * 16) ^ ((dr & 7) << 4)));
                acc[dg] = __builtin_amdgcn_mfma_f32_16x16x32_bf16(vf, pf, acc[dg], 0, 0, 0);
            }
        }
        __syncthreads();
    }

    // ---- relative-value term: acc^T[d,q] += sum_o Wrv[d,o] * exp(sband[q][o]-m)/l
    #pragma unroll 1
    for (int ks = 0; ks < 4; ks++) {
        uint4 raw = *(const uint4*)((char*)sband + ql * 272 + ks * 64 + hh * 16);
        uint32_t rr[4] = { raw.x, raw.y, raw.z, raw.w };
        uint32_t eu[4];
        #pragma unroll
        for (int i = 0; i < 4; i++) {
            float e0 = __expf(bf2f((uint16_t)(rr[i] & 0xffff)) - m_run);
            float e1 = __expf(bf2f((uint16_t)(rr[i] >> 16)) - m_run);
            eu[i] = pk_bf16(e0, e1);
        }
        bf16x8 ef = mk_frag(eu[0], eu[1], eu[2], eu[3]);
        #pragma unroll
        for (int dg = 0; dg < 4; dg++) {
            int dr = dg * 16 + q16;
            bf16x8 wf = *(const bf16x8*)((char*)Wrvlds + dr * 272 + ks * 64 + hh * 16);
            acc[dg] = __builtin_amdgcn_mfma_f32_16x16x32_bf16(wf, ef, acc[dg], 0, 0, 0);
        }
    }
    {   // o = 128 column (handled scalar; K-steps above cover o<128)
        float e128 = __expf(bf2f(sband[ql][128]) - m_run);
        #pragma unroll
        for (int dg = 0; dg < 4; dg++)
            #pragma unroll
            for (int r = 0; r < 4; r++)
                acc[dg][r] += e128 * bf2f(Wrvlds[dg * 16 + 4 * hh + r][128]);
    }

    // ---- epilogue: out[b][q][h*64+d] = acc^T / l   (float4 stores, d contiguous)
    float inv_l = 1.0f / l_run;
    #pragma unroll
    for (int dg = 0; dg < 4; dg++) {
        fx4 o4 = acc[dg] * inv_l;
        int d0 = dg * 16 + 4 * hh;
        *(fx4*)(out + (size_t)(b * SS + qglob) * (NH * DHH) + h * DHH + d0) = o4;
    }
}

// ---------------------------------------------------------------- launch
extern "C" void kernel_launch(void* const* d_in, const int* in_sizes, int n_in,
                              void* d_out, int out_size, void* d_ws, size_t ws_size,
                              hipStream_t stream) {
    const float* hs    = (const float*)d_in[0];
    const float* amask = (const float*)d_in[1];
    const float* Wq    = (const float*)d_in[2];
    const float* bq    = (const float*)d_in[3];
    const float* Wk    = (const float*)d_in[4];
    const float* bk    = (const float*)d_in[5];
    const float* Wv    = (const float*)d_in[6];
    const float* bv    = (const float*)d_in[7];
    const float* Wrk   = (const float*)d_in[8];
    const float* Wrv   = (const float*)d_in[9];
    float* out = (float*)d_out;

    char* ws = (char*)d_ws;
    uint16_t* Xb  = (uint16_t*)(ws + (0ull  << 20));  // 8 MB  bf16 X [4096][1024]
    uint16_t* Wqb = (uint16_t*)(ws + (8ull  << 20));  // 2 MB
    uint16_t* Wkb = (uint16_t*)(ws + (10ull << 20));  // 2 MB
    uint16_t* Wvb = (uint16_t*)(ws + (12ull << 20));  // 2 MB
    uint16_t* qw  = (uint16_t*)(ws + (14ull << 20));  // 8 MB  [bh][s][d]
    uint16_t* kw  = (uint16_t*)(ws + (22ull << 20));  // 8 MB
    uint16_t* vw  = (uint16_t*)(ws + (30ull << 20));  // 8 MB
    uint16_t* vtw = (uint16_t*)(ws + (38ull << 20));  // 8 MB  [bh][d][s]

    cvt_kernel<<<4096, 256, 0, stream>>>(hs, Xb, 4096 * 1024);
    cvt_kernel<<<1024, 256, 0, stream>>>(Wq, Wqb, 1024 * 1024);
    cvt_kernel<<<1024, 256, 0, stream>>>(Wk, Wkb, 1024 * 1024);
    cvt_kernel<<<1024, 256, 0, stream>>>(Wv, Wvb, 1024 * 1024);

    dim3 pg(32, 8);
    proj_gemm<<<pg, 256, 0, stream>>>(Xb, Wqb, bq, qw);
    proj_gemm<<<pg, 256, 0, stream>>>(Xb, Wkb, bk, kw);
    proj_gemm<<<pg, 256, 0, stream>>>(Xb, Wvb, bv, vw);

    vtrans<<<dim3(16, 64), 256, 0, stream>>>(vw, vtw);

    attn_kernel<<<dim3(16, 64), 256, 0, stream>>>(qw, kw, vtw, amask, Wrk, Wrv, out);
}

// Round 3
// 163.753 us; speedup vs baseline: 1.3837x; 1.3837x over previous
//
#include <hip/hip_runtime.h>
#include <stdint.h>

// Problem constants
#define BB 4
#define SS 1024
#define HIDD 1024
#define NH 16
#define DHH 64

typedef __attribute__((ext_vector_type(8))) short bf16x8;
typedef __attribute__((ext_vector_type(4))) float fx4;
typedef __attribute__((ext_vector_type(4))) int ix4;

__device__ __forceinline__ float bf2f(uint16_t u) {
    union { uint32_t u; float f; } x; x.u = ((uint32_t)u) << 16; return x.f;
}
__device__ __forceinline__ uint16_t f2bf(float f) {   // RNE
    uint32_t u = __builtin_bit_cast(uint32_t, f);
    u = u + 0x7fffu + ((u >> 16) & 1u);
    return (uint16_t)(u >> 16);
}
__device__ __forceinline__ uint32_t pk_bf16(float lo, float hi) {
    uint32_t r;
    asm volatile("v_cvt_pk_bf16_f32 %0, %1, %2" : "=v"(r) : "v"(lo), "v"(hi));
    return r;
}
__device__ __forceinline__ bf16x8 mk_frag(uint32_t u0, uint32_t u1, uint32_t u2, uint32_t u3) {
    ix4 v = { (int)u0, (int)u1, (int)u2, (int)u3 };
    return __builtin_bit_cast(bf16x8, v);
}

// ---------------------------------------------------------------- cvt f32->bf16
__global__ __launch_bounds__(256) void cvt_kernel(const float* __restrict__ in,
                                                  uint16_t* __restrict__ out, int n) {
    int i = (blockIdx.x * 256 + threadIdx.x) * 4;
    if (i < n) {
        float4 v = *(const float4*)(in + i);
        uint2 p;
        p.x = pk_bf16(v.x, v.y);
        p.y = pk_bf16(v.z, v.w);
        *(uint2*)(out + i) = p;
    }
}

// weights: 3 matrices of 1M elems in one launch (blockIdx.y selects)
__global__ __launch_bounds__(256) void cvt3_kernel(const float* __restrict__ a,
                                                   const float* __restrict__ b,
                                                   const float* __restrict__ c,
                                                   uint16_t* __restrict__ oa,
                                                   uint16_t* __restrict__ ob,
                                                   uint16_t* __restrict__ oc) {
    const float* in = (blockIdx.y == 0) ? a : (blockIdx.y == 1) ? b : c;
    uint16_t* out = (blockIdx.y == 0) ? oa : (blockIdx.y == 1) ? ob : oc;
    int i = (blockIdx.x * 256 + threadIdx.x) * 4;
    float4 v = *(const float4*)(in + i);
    uint2 p;
    p.x = pk_bf16(v.x, v.y);
    p.y = pk_bf16(v.z, v.w);
    *(uint2*)(out + i) = p;
}

// ---------------------------------------------------------------- projection GEMM (3 in one launch)
// C[m,n] = sum_k X[m,k] * W[n,k] + bias[n];  out bf16 [B][NH][S][DH] (head-major)
__global__ __launch_bounds__(256) void proj_gemm3(const uint16_t* __restrict__ X,
                                                  const uint16_t* __restrict__ Wq,
                                                  const uint16_t* __restrict__ Wk,
                                                  const uint16_t* __restrict__ Wv,
                                                  const float* __restrict__ bq,
                                                  const float* __restrict__ bk,
                                                  const float* __restrict__ bv,
                                                  uint16_t* __restrict__ oq,
                                                  uint16_t* __restrict__ ok,
                                                  uint16_t* __restrict__ ov) {
    const int z = blockIdx.z;
    const uint16_t* W = (z == 0) ? Wq : (z == 1) ? Wk : Wv;
    const float* bias = (z == 0) ? bq : (z == 1) ? bk : bv;
    uint16_t* out = (z == 0) ? oq : (z == 1) ? ok : ov;

    __shared__ uint16_t Alds[128 * 64];  // [row m][k], XOR-swizzled ^((m&7)<<4)
    __shared__ uint16_t Blds[128 * 64];  // [row n][k]
    const int tid = threadIdx.x;
    const int lane = tid & 63;
    const int wvi = tid >> 6;
    const int q16 = lane & 15;
    const int hh = lane >> 4;
    const int m0 = blockIdx.x * 128;
    const int n0 = blockIdx.y * 128;
    const int wr = wvi >> 1, wc = wvi & 1;

    fx4 zero4 = { 0.f, 0.f, 0.f, 0.f };
    fx4 acc[4][4];
    #pragma unroll
    for (int a = 0; a < 4; a++)
        #pragma unroll
        for (int c = 0; c < 4; c++) acc[a][c] = zero4;

    const int srow = tid >> 1, shalf = tid & 1;
    for (int k0 = 0; k0 < HIDD; k0 += 64) {
        // reg-staged: 64B per thread for A and B
        const uint16_t* gA = X + (size_t)(m0 + srow) * HIDD + k0 + shalf * 32;
        const uint16_t* gB = W + (size_t)(n0 + srow) * HIDD + k0 + shalf * 32;
        #pragma unroll
        for (int i = 0; i < 4; i++) {
            uint4 va = *(const uint4*)(gA + i * 8);
            uint4 vb = *(const uint4*)(gB + i * 8);
            uint32_t bo = (uint32_t)((shalf * 64 + i * 16) ^ ((srow & 7) << 4));
            *(uint4*)((char*)Alds + srow * 128 + bo) = va;
            *(uint4*)((char*)Blds + srow * 128 + bo) = vb;
        }
        __syncthreads();
        #pragma unroll
        for (int kk = 0; kk < 2; kk++) {
            bf16x8 af[4], bfr[4];
            #pragma unroll
            for (int mi = 0; mi < 4; mi++) {
                int mr = wr * 64 + mi * 16 + q16;
                af[mi] = *(const bf16x8*)((char*)Alds + mr * 128 + ((kk * 64 + hh * 16) ^ ((mr & 7) << 4)));
            }
            #pragma unroll
            for (int ni = 0; ni < 4; ni++) {
                int nr = wc * 64 + ni * 16 + q16;
                bfr[ni] = *(const bf16x8*)((char*)Blds + nr * 128 + ((kk * 64 + hh * 16) ^ ((nr & 7) << 4)));
            }
            #pragma unroll
            for (int mi = 0; mi < 4; mi++)
                #pragma unroll
                for (int ni = 0; ni < 4; ni++)
                    acc[mi][ni] = __builtin_amdgcn_mfma_f32_16x16x32_bf16(af[mi], bfr[ni], acc[mi][ni], 0, 0, 0);
        }
        __syncthreads();
    }
    // epilogue: C[m, n] -> out[b][h][s][d], bf16
    #pragma unroll
    for (int ni = 0; ni < 4; ni++) {
        int n = n0 + wc * 64 + ni * 16 + q16;
        float bvv = bias[n];
        int h = n >> 6, d = n & 63;
        #pragma unroll
        for (int mi = 0; mi < 4; mi++) {
            #pragma unroll
            for (int r = 0; r < 4; r++) {
                int m = m0 + wr * 64 + mi * 16 + 4 * hh + r;
                int b = m >> 10, s = m & 1023;
                out[(size_t)b * (NH * SS * DHH) + (size_t)h * (SS * DHH) + s * DHH + d] =
                    f2bf(acc[mi][ni][r] + bvv);
            }
        }
    }
}

// ---------------------------------------------------------------- V transpose: [bh][s][d] -> [bh][d][s]
__global__ __launch_bounds__(256) void vtrans(const uint16_t* __restrict__ v,
                                              uint16_t* __restrict__ vt) {
    __shared__ uint16_t t[64][72];
    const int tid = threadIdx.x;
    const int bh = blockIdx.y;
    const int s0 = blockIdx.x * 64;
    {
        int sl = tid >> 2, doff = (tid & 3) * 16;
        const uint16_t* src = v + (size_t)(bh * SS + s0 + sl) * 64 + doff;
        uint4 a = *(const uint4*)src;
        uint4 b2 = *(const uint4*)(src + 8);
        *(uint4*)&t[sl][doff] = a;
        *(uint4*)&t[sl][doff + 8] = b2;
    }
    __syncthreads();
    {
        int d = tid >> 2, soff = (tid & 3) * 16;
        uint32_t w[8];
        #pragma unroll
        for (int i = 0; i < 8; i++) {
            uint32_t lo = t[soff + 2 * i][d];
            uint32_t hi = t[soff + 2 * i + 1][d];
            w[i] = lo | (hi << 16);
        }
        uint16_t* dst = vt + (size_t)(bh * 64 + d) * SS + s0 + soff;
        uint4 o1 = { w[0], w[1], w[2], w[3] };
        uint4 o2 = { w[4], w[5], w[6], w[7] };
        *(uint4*)dst = o1;
        *(uint4*)(dst + 8) = o2;
    }
}

// ---------------------------------------------------------------- fused attention
// grid (16 q-tiles, 64 bh). 4 waves; wave w owns q rows [w*16, w*16+16).
// Round-1 verified core + (a) reg-prefetch of K/V tiles, (b) maskb in LDS,
// (c) Wrv staged post-loop into the recycled K/V LDS region (LDS 51.2->37.9 KB).
__global__ __launch_bounds__(256) void attn_kernel(
    const uint16_t* __restrict__ qg,   // [BH][S][64]
    const uint16_t* __restrict__ kg,   // [BH][S][64]
    const uint16_t* __restrict__ vtg,  // [BH][64][S]
    const float* __restrict__ amask,   // [B][S]
    const float* __restrict__ Wrk,     // [129][64]
    const float* __restrict__ Wrv,     // [64][129]
    float* __restrict__ out)           // [B][S][NH*64]
{
    __shared__ __align__(16) char smem[37888];
    uint16_t* Klds = (uint16_t*)smem;                         // [64][64] swz, 8192 B
    uint16_t* Vlds = (uint16_t*)(smem + 8192);                // [64][64] swz, 8192 B
    uint16_t (*sband)[136] = (uint16_t (*)[136])(smem + 16384); // 17408 B
    float* maskb = (float*)(smem + 33792);                    // 4096 B
    // after the kv loop, bytes [0,16384) are recycled as Wrv [64][128] bf16 swz.

    const int tid = threadIdx.x;
    const int lane = tid & 63;
    const int wv = tid >> 6;
    const int q16 = lane & 15;
    const int hh = lane >> 4;
    const int qt = blockIdx.x;
    const int bh = blockIdx.y;
    const int b = bh >> 4;
    const int h = bh & 15;
    const int q0 = qt * 64;
    const int ql = wv * 16 + q16;
    const int qglob = q0 + ql;

    const uint16_t* qbh = qg + (size_t)bh * (SS * 64);
    const uint16_t* kbh = kg + (size_t)bh * (SS * 64);
    const uint16_t* vbh = vtg + (size_t)bh * (64 * SS);

    // Q fragments (B-operand: col=q=lane&15, k=d contiguous)
    bf16x8 qf[2];
    #pragma unroll
    for (int ks = 0; ks < 2; ks++)
        qf[ks] = *(const bf16x8*)(qbh + (size_t)qglob * 64 + ks * 32 + hh * 8);

    // stage mask bias; explicit barrier so all later reads are ordered
    for (int i = tid; i < SS; i += 256)
        maskb[i] = (1.0f - amask[b * SS + i]) * -3.0e38f;
    __syncthreads();

    // ---- a_k = Q @ Wrk^T  ->  sband[ql][w]  (swapped: mfma(Wrk, Q) -> D[w, q])
    #pragma unroll 1
    for (int wg = 0; wg < 9; wg++) {
        fx4 a = { 0.f, 0.f, 0.f, 0.f };
        #pragma unroll
        for (int ks = 0; ks < 2; ks++) {
            int wrow = wg * 16 + q16; if (wrow > 128) wrow = 128;
            const float* p = Wrk + wrow * 64 + ks * 32 + hh * 8;
            float4 f0 = *(const float4*)p;
            float4 f1 = *(const float4*)(p + 4);
            bf16x8 af = mk_frag(pk_bf16(f0.x, f0.y), pk_bf16(f0.z, f0.w),
                                pk_bf16(f1.x, f1.y), pk_bf16(f1.z, f1.w));
            a = __builtin_amdgcn_mfma_f32_16x16x32_bf16(af, qf[ks], a, 0, 0, 0);
        }
        if (wg < 8) {
            uint2 pp;
            pp.x = pk_bf16(a[0], a[1]);
            pp.y = pk_bf16(a[2], a[3]);
            *(uint2*)&sband[ql][wg * 16 + 4 * hh] = pp;
        } else if (hh == 0) {
            sband[ql][128] = f2bf(a[0]);
        }
    }
    // poison out-of-range columns so exp() -> 0 (each wave owns its rows)
    {
        int oend = hh * 33 + 33; if (oend > 129) oend = 129;
        for (int o = hh * 33; o < oend; o++) {
            int col = qglob + o - 64;
            if (col < 0 || col >= SS) sband[ql][o] = 0xff7f;  // ~ -3.39e38 bf16
        }
    }

    float m_run = -3.0e38f, l_run = 0.f;
    fx4 acc[4];
    #pragma unroll
    for (int dg = 0; dg < 4; dg++) acc[dg] = fx4{ 0.f, 0.f, 0.f, 0.f };

    // staging geometry: 256 threads stage 64x64 bf16 K and V^T tiles (32B/thread each)
    const int srow = tid >> 2, spart = tid & 3;
    const uint32_t sb0 = (uint32_t)((spart * 32) ^ ((srow & 7) << 4));
    const uint32_t sb1 = (uint32_t)((spart * 32 + 16) ^ ((srow & 7) << 4));
    const uint16_t* gk0 = kbh + (size_t)srow * 64 + spart * 16;
    const uint16_t* gv0 = vbh + (size_t)srow * SS + spart * 16;
    uint4 ka  = *(const uint4*)gk0;
    uint4 kb2 = *(const uint4*)(gk0 + 8);
    uint4 va  = *(const uint4*)gv0;
    uint4 vb2 = *(const uint4*)(gv0 + 8);

    for (int jt = 0; jt < 16; jt++) {
        // ---- write current tile regs -> LDS
        *(uint4*)((char*)Klds + srow * 128 + sb0) = ka;
        *(uint4*)((char*)Klds + srow * 128 + sb1) = kb2;
        *(uint4*)((char*)Vlds + srow * 128 + sb0) = va;
        *(uint4*)((char*)Vlds + srow * 128 + sb1) = vb2;
        __syncthreads();

        // ---- prefetch next tile into regs (latency hides under compute below)
        if (jt < 15) {
            ka  = *(const uint4*)(gk0 + (size_t)(jt + 1) * 4096);
            kb2 = *(const uint4*)(gk0 + (size_t)(jt + 1) * 4096 + 8);
            va  = *(const uint4*)(gv0 + (jt + 1) * 64);
            vb2 = *(const uint4*)(gv0 + (jt + 1) * 64 + 8);
        }

        // ---- QK^T (swapped): sc[mg] cols = q, rows = m-local (4*hh+r)
        fx4 sc[4];
        #pragma unroll
        for (int mg = 0; mg < 4; mg++) {
            int mr = mg * 16 + q16;
            bf16x8 kf0 = *(const bf16x8*)((char*)Klds + mr * 128 + ((hh * 16) ^ ((mr & 7) << 4)));
            bf16x8 kf1 = *(const bf16x8*)((char*)Klds + mr * 128 + ((64 + hh * 16) ^ ((mr & 7) << 4)));
            fx4 s = { 0.f, 0.f, 0.f, 0.f };
            s = __builtin_amdgcn_mfma_f32_16x16x32_bf16(kf0, qf[0], s, 0, 0, 0);
            s = __builtin_amdgcn_mfma_f32_16x16x32_bf16(kf1, qf[1], s, 0, 0, 0);
            sc[mg] = s;
        }

        // ---- bias (banded), mask (LDS), band write-back, tile max
        const int dj = jt - qt;
        const bool band = (dj >= -1) && (dj <= 1);
        float tmax = -3.0e38f;
        #pragma unroll
        for (int mg = 0; mg < 4; mg++) {
            #pragma unroll
            for (int r = 0; r < 4; r++) {
                int m = jt * 64 + mg * 16 + 4 * hh + r;
                float s = sc[mg][r];
                int o = m - qglob + 64;
                bool inb = band && (o >= 0) && (o <= 128);
                if (inb) s += bf2f(sband[ql][o]);
                s += maskb[m];
                if (inb) sband[ql][o] = f2bf(s);
                sc[mg][r] = s;
                tmax = fmaxf(tmax, s);
            }
        }
        tmax = fmaxf(tmax, __shfl_xor(tmax, 16));
        tmax = fmaxf(tmax, __shfl_xor(tmax, 32));

        float m_new = fmaxf(m_run, tmax);
        float alpha = __expf(m_run - m_new);
        float psum = 0.f;
        uint32_t pk[4][2];
        #pragma unroll
        for (int mg = 0; mg < 4; mg++) {
            float p0 = __expf(sc[mg][0] - m_new);
            float p1 = __expf(sc[mg][1] - m_new);
            float p2 = __expf(sc[mg][2] - m_new);
            float p3 = __expf(sc[mg][3] - m_new);
            psum += (p0 + p1) + (p2 + p3);
            pk[mg][0] = pk_bf16(p0, p1);
            pk[mg][1] = pk_bf16(p2, p3);
        }
        psum += __shfl_xor(psum, 16);
        psum += __shfl_xor(psum, 32);
        l_run = l_run * alpha + psum;
        m_run = m_new;
        #pragma unroll
        for (int dg = 0; dg < 4; dg++) acc[dg] = acc[dg] * alpha;

        // ---- assemble P^T B-frags in-register (shuffles) and PV: acc^T += V^T P^T
        const int srcA = q16 + 16 * ((2 * hh) & 3);
        const int srcB = q16 + 16 * ((2 * hh + 1) & 3);
        const bool lo = (hh < 2);
        #pragma unroll
        for (int ks = 0; ks < 2; ks++) {
            uint32_t a0 = (uint32_t)__shfl((int)pk[2 * ks][0], srcA);
            uint32_t b0 = (uint32_t)__shfl((int)pk[2 * ks + 1][0], srcA);
            uint32_t a1 = (uint32_t)__shfl((int)pk[2 * ks][1], srcA);
            uint32_t b1 = (uint32_t)__shfl((int)pk[2 * ks + 1][1], srcA);
            uint32_t a2 = (uint32_t)__shfl((int)pk[2 * ks][0], srcB);
            uint32_t b2 = (uint32_t)__shfl((int)pk[2 * ks + 1][0], srcB);
            uint32_t a3 = (uint32_t)__shfl((int)pk[2 * ks][1], srcB);
            uint32_t b3 = (uint32_t)__shfl((int)pk[2 * ks + 1][1], srcB);
            bf16x8 pf = mk_frag(lo ? a0 : b0, lo ? a1 : b1, lo ? a2 : b2, lo ? a3 : b3);
            #pragma unroll
            for (int dg = 0; dg < 4; dg++) {
                int dr = dg * 16 + q16;
                bf16x8 vf = *(const bf16x8*)((char*)Vlds + dr * 128 + ((ks * 64 + hh * 16) ^ ((dr & 7) << 4)));
                acc[dg] = __builtin_amdgcn_mfma_f32_16x16x32_bf16(vf, pf, acc[dg], 0, 0, 0);
            }
        }
        __syncthreads();
    }

    // ---- recycle K/V LDS region as Wrv[64][128] bf16 (swizzled rows).
    // All waves passed the final in-loop barrier, so no one still reads K/V.
    {
        int r = tid >> 2, c4 = tid & 3;
        const float* src = Wrv + r * 129 + c4 * 32;
        #pragma unroll
        for (int i = 0; i < 4; i++) {
            float4 f0 = *(const float4*)(src + i * 8);
            float4 f1 = *(const float4*)(src + i * 8 + 4);
            uint4 pkv;
            pkv.x = pk_bf16(f0.x, f0.y);
            pkv.y = pk_bf16(f0.z, f0.w);
            pkv.z = pk_bf16(f1.x, f1.y);
            pkv.w = pk_bf16(f1.z, f1.w);
            *(uint4*)(smem + r * 256 + ((c4 * 64 + i * 16) ^ ((r & 7) << 4))) = pkv;
        }
    }
    __syncthreads();

    // ---- relative-value term: acc^T[d,q] += sum_o Wrv[d,o] * exp(sband[q][o]-m)
    #pragma unroll 1
    for (int ks = 0; ks < 4; ks++) {
        uint4 raw = *(const uint4*)((char*)sband + ql * 272 + ks * 64 + hh * 16);
        uint32_t rr[4] = { raw.x, raw.y, raw.z, raw.w };
        uint32_t eu[4];
        #pragma unroll
        for (int i = 0; i < 4; i++) {
            float e0 = __expf(bf2f((uint16_t)(rr[i] & 0xffff)) - m_run);
            float e1 = __expf(bf2f((uint16_t)(rr[i] >> 16)) - m_run);
            eu[i] = pk_bf16(e0, e1);
        }
        bf16x8 ef = mk_frag(eu[0], eu[1], eu[2], eu[3]);
        #pragma unroll
        for (int dg = 0; dg < 4; dg++) {
            int dr = dg * 16 + q16;
            bf16x8 wf = *(const bf16x8*)(smem + dr * 256 + ((ks * 64 + hh * 16) ^ ((dr & 7) << 4)));
            acc[dg] = __builtin_amdgcn_mfma_f32_16x16x32_bf16(wf, ef, acc[dg], 0, 0, 0);
        }
    }
    {   // o = 128 column (scalar; Wrv read from global, f32)
        float e128 = __expf(bf2f(sband[ql][128]) - m_run);
        #pragma unroll
        for (int dg = 0; dg < 4; dg++)
            #pragma unroll
            for (int r = 0; r < 4; r++)
                acc[dg][r] += e128 * Wrv[(dg * 16 + 4 * hh + r) * 129 + 128];
    }

    // ---- epilogue: out[b][q][h*64+d] = acc^T / l   (float4 stores, d contiguous)
    float inv_l = 1.0f / l_run;
    #pragma unroll
    for (int dg = 0; dg < 4; dg++) {
        fx4 o4 = acc[dg] * inv_l;
        int d0 = dg * 16 + 4 * hh;
        *(fx4*)(out + (size_t)(b * SS + qglob) * (NH * DHH) + h * DHH + d0) = o4;
    }
}

// ---------------------------------------------------------------- launch
extern "C" void kernel_launch(void* const* d_in, const int* in_sizes, int n_in,
                              void* d_out, int out_size, void* d_ws, size_t ws_size,
                              hipStream_t stream) {
    const float* hs    = (const float*)d_in[0];
    const float* amask = (const float*)d_in[1];
    const float* Wq    = (const float*)d_in[2];
    const float* bq    = (const float*)d_in[3];
    const float* Wk    = (const float*)d_in[4];
    const float* bk    = (const float*)d_in[5];
    const float* Wv    = (const float*)d_in[6];
    const float* bv    = (const float*)d_in[7];
    const float* Wrk   = (const float*)d_in[8];
    const float* Wrv   = (const float*)d_in[9];
    float* out = (float*)d_out;

    char* ws = (char*)d_ws;
    uint16_t* Xb  = (uint16_t*)(ws + (0ull  << 20));  // 8 MB  bf16 X [4096][1024]
    uint16_t* Wqb = (uint16_t*)(ws + (8ull  << 20));  // 2 MB
    uint16_t* Wkb = (uint16_t*)(ws + (10ull << 20));  // 2 MB
    uint16_t* Wvb = (uint16_t*)(ws + (12ull << 20));  // 2 MB
    uint16_t* qw  = (uint16_t*)(ws + (14ull << 20));  // 8 MB  [bh][s][d]
    uint16_t* kw  = (uint16_t*)(ws + (22ull << 20));  // 8 MB
    uint16_t* vw  = (uint16_t*)(ws + (30ull << 20));  // 8 MB
    uint16_t* vtw = (uint16_t*)(ws + (38ull << 20));  // 8 MB  [bh][d][s]

    cvt_kernel<<<4096, 256, 0, stream>>>(hs, Xb, 4096 * 1024);
    cvt3_kernel<<<dim3(1024, 3), 256, 0, stream>>>(Wq, Wk, Wv, Wqb, Wkb, Wvb);

    proj_gemm3<<<dim3(32, 8, 3), 256, 0, stream>>>(Xb, Wqb, Wkb, Wvb, bq, bk, bv, qw, kw, vw);

    vtrans<<<dim3(16, 64), 256, 0, stream>>>(vw, vtw);

    attn_kernel<<<dim3(16, 64), 256, 0, stream>>>(qw, kw, vtw, amask, Wrk, Wrv, out);
}